// Round 14
// baseline (149.147 us; speedup 1.0000x reference)
//
#include <hip/hip_runtime.h>
#include <hip/hip_bf16.h>

// GCNConv: coarse bin (64 tgts/bucket) -> fused per-bucket {LDS counting sort
// + per-node wave gather + epilogue}. No fp32 global atomics anywhere.
// agg[c] = dinv[c] * ( xs[c] + sum_{e: col[e]==c} xs[row[e]] ),
//   xs[i] = (x@W)[i] * dinv[i],  dinv[i] = rsqrt(1 + indeg(i))
// out = dropout(tanh(agg + b)), JAX partitionable-threefry key (0,42), p_keep=0.9:
//   bits[p] = o0^o1 of threefry((0,42), 0, p); u = bitcast(bits>>9|0x3f800000)-1; keep = u<0.9.
//
// R8: __shfl sources must be ACTIVE lanes. R14: inner loop now reads src ids
//   from LDS (broadcast reads) instead of shfl — predication is safe again.
// R13 profile: k_agg 56us VALU-issue-bound; ~93us was plumbing. R14 fuses
//   sortb into agg (k_sagg), deletes noff + packed writeback + one dispatch.
//
// ws (19.6 MB): dinv f32[NN] | xsh bf16[NN*64] | packed u32[NE] |
//               bhist i32[NBUCK] | bstart i32[NBUCK+1] | bcur i32[NBUCK]

#define NN 100000
#define NE 1600000
#define NBUCK 1563
#define P1B 128
#define P1T 1024
#define CHUNK 12500         // P1B * CHUNK == NE
#define STAGE_CAP 2560      // > mean(1024) + 48 sigma; scan-mode if exceeded

// ---------------- Threefry2x32 (JAX-exact) ----------------
__device__ __forceinline__ unsigned rotl32(unsigned x, int r) {
    return (x << r) | (x >> (32 - r));
}

__device__ __forceinline__ void threefry2x32(unsigned k0, unsigned k1,
                                             unsigned x0, unsigned x1,
                                             unsigned& o0, unsigned& o1) {
    const unsigned ks0 = k0, ks1 = k1, ks2 = k0 ^ k1 ^ 0x1BD11BDAu;
    x0 += ks0; x1 += ks1;
    x0 += x1; x1 = rotl32(x1, 13); x1 ^= x0;
    x0 += x1; x1 = rotl32(x1, 15); x1 ^= x0;
    x0 += x1; x1 = rotl32(x1, 26); x1 ^= x0;
    x0 += x1; x1 = rotl32(x1, 6);  x1 ^= x0;
    x0 += ks1; x1 += ks2 + 1u;
    x0 += x1; x1 = rotl32(x1, 17); x1 ^= x0;
    x0 += x1; x1 = rotl32(x1, 29); x1 ^= x0;
    x0 += x1; x1 = rotl32(x1, 16); x1 ^= x0;
    x0 += x1; x1 = rotl32(x1, 24); x1 ^= x0;
    x0 += ks2; x1 += ks0 + 2u;
    x0 += x1; x1 = rotl32(x1, 13); x1 ^= x0;
    x0 += x1; x1 = rotl32(x1, 15); x1 ^= x0;
    x0 += x1; x1 = rotl32(x1, 26); x1 ^= x0;
    x0 += x1; x1 = rotl32(x1, 6);  x1 ^= x0;
    x0 += ks0; x1 += ks1 + 3u;
    x0 += x1; x1 = rotl32(x1, 17); x1 ^= x0;
    x0 += x1; x1 = rotl32(x1, 29); x1 ^= x0;
    x0 += x1; x1 = rotl32(x1, 16); x1 ^= x0;
    x0 += x1; x1 = rotl32(x1, 24); x1 ^= x0;
    x0 += ks1; x1 += ks2 + 4u;
    x0 += x1; x1 = rotl32(x1, 13); x1 ^= x0;
    x0 += x1; x1 = rotl32(x1, 15); x1 ^= x0;
    x0 += x1; x1 = rotl32(x1, 26); x1 ^= x0;
    x0 += x1; x1 = rotl32(x1, 6);  x1 ^= x0;
    x0 += ks2; x1 += ks0 + 5u;
    o0 = x0; o1 = x1;
}

// ---------------- Kernels ----------------
__global__ __launch_bounds__(P1T) void k_bhist(const int* __restrict__ ei,
                                               int* __restrict__ bhist) {
    __shared__ int h[NBUCK];
    const int tid = threadIdx.x;
    for (int i = tid; i < NBUCK; i += P1T) h[i] = 0;
    __syncthreads();
    const int base = blockIdx.x * CHUNK;
    for (int i = tid; i < CHUNK; i += P1T) {
        const unsigned t = (unsigned)ei[NE + base + i];
        if (t < NN) atomicAdd(&h[t >> 6], 1);
    }
    __syncthreads();
    for (int i = tid; i < NBUCK; i += P1T) {
        const int v = h[i];
        if (v) atomicAdd(&bhist[i], v);
    }
}

__global__ __launch_bounds__(1024) void k_bscan(const int* __restrict__ bhist,
                                                int* __restrict__ bstart,
                                                int* __restrict__ bcur) {
    __shared__ int s[2048];
    const int t = threadIdx.x;
    const int i0 = t, i1 = t + 1024;
    const int c0 = (i0 < NBUCK) ? bhist[i0] : 0;
    const int c1 = (i1 < NBUCK) ? bhist[i1] : 0;
    s[i0] = c0; s[i1] = c1;
    __syncthreads();
    for (int d = 1; d < 2048; d <<= 1) {
        const int a0 = (i0 >= d) ? s[i0 - d] : 0;
        const int a1 = (i1 >= d) ? s[i1 - d] : 0;
        __syncthreads();
        s[i0] += a0; s[i1] += a1;
        __syncthreads();
    }
    if (i0 < NBUCK) { const int b = s[i0] - c0; bstart[i0] = b; bcur[i0] = b; }
    if (i1 < NBUCK) { const int b = s[i1] - c1; bstart[i1] = b; bcur[i1] = b; }
    if (t == 0) bstart[NBUCK] = NE;
}

__global__ __launch_bounds__(P1T) void k_p1(const int* __restrict__ ei,
                                            int* __restrict__ bcur,
                                            unsigned* __restrict__ packed) {
    __shared__ int hb[NBUCK];
    __shared__ int lc[NBUCK];
    const int tid = threadIdx.x;
    for (int i = tid; i < NBUCK; i += P1T) { hb[i] = 0; lc[i] = 0; }
    __syncthreads();
    const int base = blockIdx.x * CHUNK;
    for (int i = tid; i < CHUNK; i += P1T) {
        const unsigned t = (unsigned)ei[NE + base + i];
        if (t < NN) atomicAdd(&hb[t >> 6], 1);
    }
    __syncthreads();
    for (int i = tid; i < NBUCK; i += P1T) {
        const int h = hb[i];
        hb[i] = h ? atomicAdd(&bcur[i], h) : 0;
    }
    __syncthreads();
    for (int i = tid; i < CHUNK; i += P1T) {
        const unsigned t = (unsigned)ei[NE + base + i];
        if (t >= NN) continue;
        const unsigned src = (unsigned)ei[base + i];
        const int bk = t >> 6;
        const unsigned pos = (unsigned)(hb[bk] + atomicAdd(&lc[bk], 1));
        if (pos < NE) packed[pos] = src | ((t & 63u) << 17);
    }
}

// Per-bucket degree hist -> dinv (needed by k_xw before k_sagg).
__global__ __launch_bounds__(256) void k_deg(const unsigned* __restrict__ packed,
                                             const int* __restrict__ bstart,
                                             float* __restrict__ dinv) {
    __shared__ int hist[64];
    const int tid = threadIdx.x;
    const int b = blockIdx.x;
    int s = bstart[b], e = bstart[b + 1];
    if (s < 0) s = 0;
    if (e > NE) e = NE;
    if (tid < 64) hist[tid] = 0;
    __syncthreads();
    for (int i = s + tid; i < e; i += 256) atomicAdd(&hist[packed[i] >> 17], 1);
    __syncthreads();
    if (tid < 64) {
        const int c = b * 64 + tid;
        if (c < NN) dinv[c] = rsqrtf(1.0f + (float)hist[tid]);
    }
}

// x@W: W register-resident, x rows staged in LDS, distributed per-row via
// ds_read_b128 broadcasts + 64 register FMAs. 64 rows/block, 16/wave.
__global__ __launch_bounds__(256) void k_xw(const float* __restrict__ x,
                                            const float* __restrict__ W,
                                            const float* __restrict__ dinv,
                                            __hip_bfloat16* __restrict__ xsh) {
    __shared__ float Wl[64 * 64];   // 16 KB
    __shared__ float xl[64 * 64];   // 16 KB
    const int tid = threadIdx.x;
    for (int i = tid; i < 64 * 64; i += 256) Wl[i] = W[i];  // coalesced
    const int row0 = blockIdx.x * 64;
    {
        const int nfl4 = ((NN - row0) < 64 ? (NN - row0) : 64) * 16;
        const float4* __restrict__ xg = (const float4*)(x + (size_t)row0 * 64);
        float4* __restrict__ xl4 = (float4*)xl;
        for (int i = tid; i < nfl4; i += 256) xl4[i] = xg[i];
    }
    __syncthreads();
    const int wid = tid >> 6, lane = tid & 63;
    float wreg[64];
#pragma unroll
    for (int k = 0; k < 64; ++k) wreg[k] = Wl[k * 64 + lane];
    const int rbase = wid * 16;
#pragma unroll 1
    for (int r = 0; r < 16; ++r) {
        const int row = row0 + rbase + r;
        if (row >= NN) break;  // wave-uniform
        const float4* __restrict__ xr4 = (const float4*)(xl + (rbase + r) * 64);
        float sum = 0.0f;
#pragma unroll
        for (int q = 0; q < 16; ++q) {
            const float4 xv = xr4[q];  // ds_read_b128 broadcast
            sum = fmaf(xv.x, wreg[4 * q + 0], sum);
            sum = fmaf(xv.y, wreg[4 * q + 1], sum);
            sum = fmaf(xv.z, wreg[4 * q + 2], sum);
            sum = fmaf(xv.w, wreg[4 * q + 3], sum);
        }
        xsh[(size_t)row * 64 + lane] = __float2bfloat16(sum * dinv[row]);
    }
}

// Fused per-bucket sort + aggregate + epilogue. One block per bucket:
//   hist (global read #1) -> prefix+dinv -> LDS counting sort (global read #2)
//   -> per-node wave gather reading src ids from LDS (broadcast ds_read, no
//   shfl, predication-safe) -> tanh + threefry dropout, coalesced out writes.
__global__ __launch_bounds__(256) void k_sagg(const unsigned* __restrict__ packed,
                                              const int* __restrict__ bstart,
                                              const __hip_bfloat16* __restrict__ xsh,
                                              const float* __restrict__ bias,
                                              float* __restrict__ out) {
    __shared__ unsigned sorted[STAGE_CAP];  // 10.25 KB
    __shared__ int hist[64];
    __shared__ int pref[64];
    __shared__ int cur[64];
    __shared__ float sdinv[64];
    const int tid = threadIdx.x;
    const int b = blockIdx.x;
    int s = bstart[b], e = bstart[b + 1];
    if (s < 0) s = 0;
    if (e > NE) e = NE;
    if (e < s) e = s;
    const int seg = e - s;
    const bool oversize = (seg > STAGE_CAP);
    if (tid < 64) hist[tid] = 0;
    __syncthreads();
    for (int i = s + tid; i < e; i += 256) atomicAdd(&hist[packed[i] >> 17], 1);
    __syncthreads();
    if (tid == 0) {
        int run = 0;
        for (int t = 0; t < 64; ++t) { pref[t] = run; run += hist[t]; }
    }
    __syncthreads();
    if (tid < 64) {
        cur[tid] = pref[tid];
        sdinv[tid] = rsqrtf(1.0f + (float)hist[tid]);
    }
    __syncthreads();
    if (!oversize) {
        for (int i = s + tid; i < e; i += 256) {
            const unsigned pk = packed[i];
            const int pos = atomicAdd(&cur[pk >> 17], 1);
            sorted[pos] = pk & 0x1FFFFu;
        }
    }
    __syncthreads();

    const int wid = tid >> 6, lane = tid & 63, g = lane >> 5, hl = lane & 31;
    const unsigned* __restrict__ xs2 = (const unsigned*)xsh;  // bf16 pairs
    const float bv = bias[lane];
#pragma unroll 1
    for (int t = 0; t < 16; ++t) {
        const int nl = wid * 16 + t;
        const int c = b * 64 + nl;
        if (c >= NN) break;  // wave-uniform
        const int off = pref[nl];
        int deg = hist[nl];
        deg = (deg < 0) ? 0 : (deg > seg ? seg : deg);  // defensive
        float2 ac0 = {0.f, 0.f}, ac1 = {0.f, 0.f}, ac2 = {0.f, 0.f}, ac3 = {0.f, 0.f};
        if (g == 0) {  // self-loop term (counted once)
            const unsigned v = xs2[(size_t)c * 32 + hl];
            ac0.x += __uint_as_float(v << 16);
            ac0.y += __uint_as_float(v & 0xffff0000u);
        }
        if (!oversize) {
            int j = 0;
            for (; j + 7 < deg; j += 8) {  // 8 edges, 4 pair-chains
                const int s0 = (int)sorted[off + j + g];      // LDS broadcast
                const int s1 = (int)sorted[off + j + 2 + g];
                const int s2 = (int)sorted[off + j + 4 + g];
                const int s3 = (int)sorted[off + j + 6 + g];
                const unsigned v0 = xs2[(size_t)s0 * 32 + hl];
                const unsigned v1 = xs2[(size_t)s1 * 32 + hl];
                const unsigned v2 = xs2[(size_t)s2 * 32 + hl];
                const unsigned v3 = xs2[(size_t)s3 * 32 + hl];
                ac0.x += __uint_as_float(v0 << 16); ac0.y += __uint_as_float(v0 & 0xffff0000u);
                ac1.x += __uint_as_float(v1 << 16); ac1.y += __uint_as_float(v1 & 0xffff0000u);
                ac2.x += __uint_as_float(v2 << 16); ac2.y += __uint_as_float(v2 & 0xffff0000u);
                ac3.x += __uint_as_float(v3 << 16); ac3.y += __uint_as_float(v3 & 0xffff0000u);
            }
            for (; j < deg; j += 2) {  // tail: predication safe (no shfl)
                const int eo = j + g;
                if (eo < deg) {
                    const int s0 = (int)sorted[off + eo];
                    const unsigned v = xs2[(size_t)s0 * 32 + hl];
                    ac0.x += __uint_as_float(v << 16);
                    ac0.y += __uint_as_float(v & 0xffff0000u);
                }
            }
        } else {  // scan-mode fallback: unsorted global segment, tl-tagged
            if (g == 0) {
                const unsigned tl = (unsigned)nl;
                for (int i = s; i < e; ++i) {
                    const unsigned pk = packed[i];
                    if ((pk >> 17) == tl) {
                        const unsigned v = xs2[(size_t)(pk & 0x1FFFFu) * 32 + hl];
                        ac0.x += __uint_as_float(v << 16);
                        ac0.y += __uint_as_float(v & 0xffff0000u);
                    }
                }
            }
        }
        float alo = (ac0.x + ac1.x) + (ac2.x + ac3.x);
        float ahi = (ac0.y + ac1.y) + (ac2.y + ac3.y);
        alo += __shfl_xor(alo, 32);  // combine edge-parity halves
        ahi += __shfl_xor(ahi, 32);
        const float va = __shfl(alo, lane >> 1);  // redistribute to dims
        const float vb = __shfl(ahi, lane >> 1);
        const float a = (lane & 1) ? vb : va;
        const int p = c * 64 + lane;
        unsigned o0, o1;
        threefry2x32(0u, 42u, 0u, (unsigned)p, o0, o1);
        const unsigned bits = o0 ^ o1;
        const float u = __uint_as_float((bits >> 9) | 0x3f800000u) - 1.0f;
        const float h = tanhf(sdinv[nl] * a + bv);
        out[p] = (u < 0.9f) ? h / 0.9f : 0.0f;
    }
}

extern "C" void kernel_launch(void* const* d_in, const int* in_sizes, int n_in,
                              void* d_out, int out_size, void* d_ws, size_t ws_size,
                              hipStream_t stream) {
    const float* x  = (const float*)d_in[0];
    const float* W  = (const float*)d_in[1];
    const float* b  = (const float*)d_in[2];
    const int*   ei = (const int*)d_in[3];
    float* out = (float*)d_out;

    float* dinv = (float*)d_ws;                             // f32[NN]
    __hip_bfloat16* xsh = (__hip_bfloat16*)(dinv + NN);     // bf16[NN*64]
    unsigned* packed = (unsigned*)(xsh + (size_t)NN * 64);  // u32[NE]
    int* bhist  = (int*)(packed + NE);                      // i32[NBUCK]
    int* bstart = bhist + NBUCK;                            // i32[NBUCK+1]
    int* bcur   = bstart + NBUCK + 1;                       // i32[NBUCK]

    hipMemsetAsync(bhist, 0, NBUCK * sizeof(int), stream);
    k_bhist<<<P1B, P1T, 0, stream>>>(ei, bhist);
    k_bscan<<<1, 1024, 0, stream>>>(bhist, bstart, bcur);
    k_p1<<<P1B, P1T, 0, stream>>>(ei, bcur, packed);
    k_deg<<<NBUCK, 256, 0, stream>>>(packed, bstart, dinv);
    k_xw<<<(NN + 63) / 64, 256, 0, stream>>>(x, W, dinv, xsh);
    k_sagg<<<NBUCK, 256, 0, stream>>>(packed, bstart, xsh, b, out);
}

// Round 15
// 145.639 us; speedup vs baseline: 1.0241x; 1.0241x over previous
//
#include <hip/hip_runtime.h>
#include <hip/hip_bf16.h>

// GCNConv: coarse bin (64 tgts/bucket) -> fused per-half-bucket {LDS counting
// sort + per-node wave gather + epilogue}. No fp32 global atomics anywhere.
// agg[c] = dinv[c] * ( xs[c] + sum_{e: col[e]==c} xs[row[e]] ),
//   xs[i] = (x@W)[i] * dinv[i],  dinv[i] = rsqrt(1 + indeg(i))
// out = dropout(tanh(agg + b)), JAX partitionable-threefry key (0,42), p_keep=0.9:
//   bits[p] = o0^o1 of threefry((0,42), 0, p); u = bitcast(bits>>9|0x3f800000)-1; keep = u<0.9.
//
// R8: __shfl sources must be ACTIVE lanes (loops with shfl stay uniform).
// R14 lesson: 1563 fat blocks = 6 blocks/CU total -> 48% occupancy. R15:
//   2 blocks/bucket (3126 blocks, 32 nodes each) + quarter-lane uint2 gather
//   (16 lanes x 4 dims per edge: half the loads & addr-calc per edge).
//
// ws (19.6 MB): dinv f32[NN] | xsh bf16[NN*64] | packed u32[NE] |
//               bhist i32[NBUCK] | bstart i32[NBUCK+1] | bcur i32[NBUCK]

#define NN 100000
#define NE 1600000
#define NBUCK 1563
#define P1B 128
#define P1T 1024
#define CHUNK 12500         // P1B * CHUNK == NE
#define HCAP 1536           // per-half-bucket LDS sort capacity (mean 512)

// ---------------- Threefry2x32 (JAX-exact) ----------------
__device__ __forceinline__ unsigned rotl32(unsigned x, int r) {
    return (x << r) | (x >> (32 - r));
}

__device__ __forceinline__ void threefry2x32(unsigned k0, unsigned k1,
                                             unsigned x0, unsigned x1,
                                             unsigned& o0, unsigned& o1) {
    const unsigned ks0 = k0, ks1 = k1, ks2 = k0 ^ k1 ^ 0x1BD11BDAu;
    x0 += ks0; x1 += ks1;
    x0 += x1; x1 = rotl32(x1, 13); x1 ^= x0;
    x0 += x1; x1 = rotl32(x1, 15); x1 ^= x0;
    x0 += x1; x1 = rotl32(x1, 26); x1 ^= x0;
    x0 += x1; x1 = rotl32(x1, 6);  x1 ^= x0;
    x0 += ks1; x1 += ks2 + 1u;
    x0 += x1; x1 = rotl32(x1, 17); x1 ^= x0;
    x0 += x1; x1 = rotl32(x1, 29); x1 ^= x0;
    x0 += x1; x1 = rotl32(x1, 16); x1 ^= x0;
    x0 += x1; x1 = rotl32(x1, 24); x1 ^= x0;
    x0 += ks2; x1 += ks0 + 2u;
    x0 += x1; x1 = rotl32(x1, 13); x1 ^= x0;
    x0 += x1; x1 = rotl32(x1, 15); x1 ^= x0;
    x0 += x1; x1 = rotl32(x1, 26); x1 ^= x0;
    x0 += x1; x1 = rotl32(x1, 6);  x1 ^= x0;
    x0 += ks0; x1 += ks1 + 3u;
    x0 += x1; x1 = rotl32(x1, 17); x1 ^= x0;
    x0 += x1; x1 = rotl32(x1, 29); x1 ^= x0;
    x0 += x1; x1 = rotl32(x1, 16); x1 ^= x0;
    x0 += x1; x1 = rotl32(x1, 24); x1 ^= x0;
    x0 += ks1; x1 += ks2 + 4u;
    x0 += x1; x1 = rotl32(x1, 13); x1 ^= x0;
    x0 += x1; x1 = rotl32(x1, 15); x1 ^= x0;
    x0 += x1; x1 = rotl32(x1, 26); x1 ^= x0;
    x0 += x1; x1 = rotl32(x1, 6);  x1 ^= x0;
    x0 += ks2; x1 += ks0 + 5u;
    o0 = x0; o1 = x1;
}

// ---------------- Kernels ----------------
__global__ __launch_bounds__(P1T) void k_bhist(const int* __restrict__ ei,
                                               int* __restrict__ bhist) {
    __shared__ int h[NBUCK];
    const int tid = threadIdx.x;
    for (int i = tid; i < NBUCK; i += P1T) h[i] = 0;
    __syncthreads();
    const int base = blockIdx.x * CHUNK;
    for (int i = tid; i < CHUNK; i += P1T) {
        const unsigned t = (unsigned)ei[NE + base + i];
        if (t < NN) atomicAdd(&h[t >> 6], 1);
    }
    __syncthreads();
    for (int i = tid; i < NBUCK; i += P1T) {
        const int v = h[i];
        if (v) atomicAdd(&bhist[i], v);
    }
}

__global__ __launch_bounds__(1024) void k_bscan(const int* __restrict__ bhist,
                                                int* __restrict__ bstart,
                                                int* __restrict__ bcur) {
    __shared__ int s[2048];
    const int t = threadIdx.x;
    const int i0 = t, i1 = t + 1024;
    const int c0 = (i0 < NBUCK) ? bhist[i0] : 0;
    const int c1 = (i1 < NBUCK) ? bhist[i1] : 0;
    s[i0] = c0; s[i1] = c1;
    __syncthreads();
    for (int d = 1; d < 2048; d <<= 1) {
        const int a0 = (i0 >= d) ? s[i0 - d] : 0;
        const int a1 = (i1 >= d) ? s[i1 - d] : 0;
        __syncthreads();
        s[i0] += a0; s[i1] += a1;
        __syncthreads();
    }
    if (i0 < NBUCK) { const int b = s[i0] - c0; bstart[i0] = b; bcur[i0] = b; }
    if (i1 < NBUCK) { const int b = s[i1] - c1; bstart[i1] = b; bcur[i1] = b; }
    if (t == 0) bstart[NBUCK] = NE;
}

__global__ __launch_bounds__(P1T) void k_p1(const int* __restrict__ ei,
                                            int* __restrict__ bcur,
                                            unsigned* __restrict__ packed) {
    __shared__ int hb[NBUCK];
    __shared__ int lc[NBUCK];
    const int tid = threadIdx.x;
    for (int i = tid; i < NBUCK; i += P1T) { hb[i] = 0; lc[i] = 0; }
    __syncthreads();
    const int base = blockIdx.x * CHUNK;
    for (int i = tid; i < CHUNK; i += P1T) {
        const unsigned t = (unsigned)ei[NE + base + i];
        if (t < NN) atomicAdd(&hb[t >> 6], 1);
    }
    __syncthreads();
    for (int i = tid; i < NBUCK; i += P1T) {
        const int h = hb[i];
        hb[i] = h ? atomicAdd(&bcur[i], h) : 0;
    }
    __syncthreads();
    for (int i = tid; i < CHUNK; i += P1T) {
        const unsigned t = (unsigned)ei[NE + base + i];
        if (t >= NN) continue;
        const unsigned src = (unsigned)ei[base + i];
        const int bk = t >> 6;
        const unsigned pos = (unsigned)(hb[bk] + atomicAdd(&lc[bk], 1));
        if (pos < NE) packed[pos] = src | ((t & 63u) << 17);
    }
}

// Per-bucket degree hist -> dinv (needed by k_xw before k_sagg).
__global__ __launch_bounds__(256) void k_deg(const unsigned* __restrict__ packed,
                                             const int* __restrict__ bstart,
                                             float* __restrict__ dinv) {
    __shared__ int hist[64];
    const int tid = threadIdx.x;
    const int b = blockIdx.x;
    int s = bstart[b], e = bstart[b + 1];
    if (s < 0) s = 0;
    if (e > NE) e = NE;
    if (tid < 64) hist[tid] = 0;
    __syncthreads();
    for (int i = s + tid; i < e; i += 256) atomicAdd(&hist[packed[i] >> 17], 1);
    __syncthreads();
    if (tid < 64) {
        const int c = b * 64 + tid;
        if (c < NN) dinv[c] = rsqrtf(1.0f + (float)hist[tid]);
    }
}

// x@W: W register-resident, x rows staged in LDS, distributed per-row via
// ds_read_b128 broadcasts + 64 register FMAs. 64 rows/block, 16/wave.
__global__ __launch_bounds__(256) void k_xw(const float* __restrict__ x,
                                            const float* __restrict__ W,
                                            const float* __restrict__ dinv,
                                            __hip_bfloat16* __restrict__ xsh) {
    __shared__ float Wl[64 * 64];   // 16 KB
    __shared__ float xl[64 * 64];   // 16 KB
    const int tid = threadIdx.x;
    for (int i = tid; i < 64 * 64; i += 256) Wl[i] = W[i];  // coalesced
    const int row0 = blockIdx.x * 64;
    {
        const int nfl4 = ((NN - row0) < 64 ? (NN - row0) : 64) * 16;
        const float4* __restrict__ xg = (const float4*)(x + (size_t)row0 * 64);
        float4* __restrict__ xl4 = (float4*)xl;
        for (int i = tid; i < nfl4; i += 256) xl4[i] = xg[i];
    }
    __syncthreads();
    const int wid = tid >> 6, lane = tid & 63;
    float wreg[64];
#pragma unroll
    for (int k = 0; k < 64; ++k) wreg[k] = Wl[k * 64 + lane];
    const int rbase = wid * 16;
#pragma unroll 1
    for (int r = 0; r < 16; ++r) {
        const int row = row0 + rbase + r;
        if (row >= NN) break;  // wave-uniform
        const float4* __restrict__ xr4 = (const float4*)(xl + (rbase + r) * 64);
        float sum = 0.0f;
#pragma unroll
        for (int q = 0; q < 16; ++q) {
            const float4 xv = xr4[q];  // ds_read_b128 broadcast
            sum = fmaf(xv.x, wreg[4 * q + 0], sum);
            sum = fmaf(xv.y, wreg[4 * q + 1], sum);
            sum = fmaf(xv.z, wreg[4 * q + 2], sum);
            sum = fmaf(xv.w, wreg[4 * q + 3], sum);
        }
        xsh[(size_t)row * 64 + lane] = __float2bfloat16(sum * dinv[row]);
    }
}

// Fused per-HALF-bucket sort + aggregate + epilogue. 2 blocks per bucket;
// each owns 32 nodes: hist(its half) -> prefix+dinv -> LDS counting sort ->
// per-node gather with quarter-lanes (q=lane>>4 edge slot, sl=lane&15 holds
// dims 4sl..4sl+3 as one uint2). No shfl in predicated code; uniform combines.
__global__ __launch_bounds__(256) void k_sagg(const unsigned* __restrict__ packed,
                                              const int* __restrict__ bstart,
                                              const __hip_bfloat16* __restrict__ xsh,
                                              const float* __restrict__ bias,
                                              float* __restrict__ out) {
    __shared__ unsigned sorted[HCAP];  // 6 KB
    __shared__ int hist[32];
    __shared__ int pref[32];
    __shared__ int cur[32];
    __shared__ float sdinv[32];
    const int tid = threadIdx.x;
    const int b = blockIdx.x >> 1;         // bucket
    const unsigned half = blockIdx.x & 1;  // 0: tl 0..31, 1: tl 32..63
    int s = bstart[b], e = bstart[b + 1];
    if (s < 0) s = 0;
    if (e > NE) e = NE;
    if (e < s) e = s;
    if (tid < 32) hist[tid] = 0;
    __syncthreads();
    for (int i = s + tid; i < e; i += 256) {
        const unsigned pk = packed[i];
        if (((pk >> 22) & 1u) == half) atomicAdd(&hist[(pk >> 17) & 31u], 1);
    }
    __syncthreads();
    if (tid == 0) {
        int run = 0;
        for (int t = 0; t < 32; ++t) { pref[t] = run; run += hist[t]; }
    }
    __syncthreads();
    const int hcnt = pref[31] + hist[31];
    const bool oversize = (hcnt > HCAP);
    if (tid < 32) {
        cur[tid] = pref[tid];
        sdinv[tid] = rsqrtf(1.0f + (float)hist[tid]);
    }
    __syncthreads();
    if (!oversize) {
        for (int i = s + tid; i < e; i += 256) {
            const unsigned pk = packed[i];
            if (((pk >> 22) & 1u) == half) {
                const int pos = atomicAdd(&cur[(pk >> 17) & 31u], 1);
                if (pos < HCAP) sorted[pos] = pk & 0x1FFFFu;
            }
        }
    }
    __syncthreads();

    const int wid = tid >> 6, lane = tid & 63;
    const int q = lane >> 4, sl = lane & 15;   // quarter, dim-quad
    const uint2* __restrict__ xs4 = (const uint2*)xsh;  // 4 bf16 per elem
    const float bv = bias[lane];
#pragma unroll 1
    for (int t = 0; t < 8; ++t) {
        const int nl = wid * 8 + t;            // 0..31 within half
        const int c = b * 64 + (int)half * 32 + nl;
        if (c >= NN) break;  // wave-uniform
        const int off = pref[nl];
        int deg = hist[nl];
        deg = (deg < 0) ? 0 : (deg > hcnt ? hcnt : deg);  // defensive
        float4 a0 = {0.f, 0.f, 0.f, 0.f}, a1 = {0.f, 0.f, 0.f, 0.f};
        if (q == 0) {  // self-loop term (counted once)
            const uint2 v = xs4[(size_t)c * 16 + sl];
            a0.x += __uint_as_float(v.x << 16);
            a0.y += __uint_as_float(v.x & 0xffff0000u);
            a0.z += __uint_as_float(v.y << 16);
            a0.w += __uint_as_float(v.y & 0xffff0000u);
        }
        if (!oversize) {
            int j = 0;
            for (; j + 7 < deg; j += 8) {  // 8 edges: 2 chains x 4 quarters
                const int s0 = (int)sorted[off + j + q];
                const int s1 = (int)sorted[off + j + 4 + q];
                const uint2 v0 = xs4[(size_t)s0 * 16 + sl];
                const uint2 v1 = xs4[(size_t)s1 * 16 + sl];
                a0.x += __uint_as_float(v0.x << 16); a0.y += __uint_as_float(v0.x & 0xffff0000u);
                a0.z += __uint_as_float(v0.y << 16); a0.w += __uint_as_float(v0.y & 0xffff0000u);
                a1.x += __uint_as_float(v1.x << 16); a1.y += __uint_as_float(v1.x & 0xffff0000u);
                a1.z += __uint_as_float(v1.y << 16); a1.w += __uint_as_float(v1.y & 0xffff0000u);
            }
            for (; j < deg; j += 4) {  // tail: predicated loads, no shfl
                const int eo = j + q;
                if (eo < deg) {
                    const int s0 = (int)sorted[off + eo];
                    const uint2 v = xs4[(size_t)s0 * 16 + sl];
                    a0.x += __uint_as_float(v.x << 16);
                    a0.y += __uint_as_float(v.x & 0xffff0000u);
                    a0.z += __uint_as_float(v.y << 16);
                    a0.w += __uint_as_float(v.y & 0xffff0000u);
                }
            }
        } else {  // scan-mode fallback: unsorted global segment, tl-tagged
            if (q == 0) {
                const unsigned tl = (unsigned)((int)half * 32 + nl);
                for (int i = s; i < e; ++i) {
                    const unsigned pk = packed[i];
                    if ((pk >> 17) == tl) {
                        const uint2 v = xs4[(size_t)(pk & 0x1FFFFu) * 16 + sl];
                        a0.x += __uint_as_float(v.x << 16);
                        a0.y += __uint_as_float(v.x & 0xffff0000u);
                        a0.z += __uint_as_float(v.y << 16);
                        a0.w += __uint_as_float(v.y & 0xffff0000u);
                    }
                }
            }
        }
        // combine chains, then quarters (uniform shfls, all lanes active)
        float ax = a0.x + a1.x, ay = a0.y + a1.y;
        float az = a0.z + a1.z, aw = a0.w + a1.w;
        ax += __shfl_xor(ax, 16); ax += __shfl_xor(ax, 32);
        ay += __shfl_xor(ay, 16); ay += __shfl_xor(ay, 32);
        az += __shfl_xor(az, 16); az += __shfl_xor(az, 32);
        aw += __shfl_xor(aw, 16); aw += __shfl_xor(aw, 32);
        // redistribute: lane l takes dim l = comp (l&3) from lane l>>2
        const float sx = __shfl(ax, lane >> 2);
        const float sy = __shfl(ay, lane >> 2);
        const float sz = __shfl(az, lane >> 2);
        const float sw = __shfl(aw, lane >> 2);
        const float ab = (lane & 1) ? sy : sx;
        const float cd = (lane & 1) ? sw : sz;
        const float a = (lane & 2) ? cd : ab;
        const int p = c * 64 + lane;
        unsigned o0, o1;
        threefry2x32(0u, 42u, 0u, (unsigned)p, o0, o1);
        const unsigned bits = o0 ^ o1;
        const float u = __uint_as_float((bits >> 9) | 0x3f800000u) - 1.0f;
        const float h = tanhf(sdinv[nl] * a + bv);
        out[p] = (u < 0.9f) ? h / 0.9f : 0.0f;
    }
}

extern "C" void kernel_launch(void* const* d_in, const int* in_sizes, int n_in,
                              void* d_out, int out_size, void* d_ws, size_t ws_size,
                              hipStream_t stream) {
    const float* x  = (const float*)d_in[0];
    const float* W  = (const float*)d_in[1];
    const float* b  = (const float*)d_in[2];
    const int*   ei = (const int*)d_in[3];
    float* out = (float*)d_out;

    float* dinv = (float*)d_ws;                             // f32[NN]
    __hip_bfloat16* xsh = (__hip_bfloat16*)(dinv + NN);     // bf16[NN*64]
    unsigned* packed = (unsigned*)(xsh + (size_t)NN * 64);  // u32[NE]
    int* bhist  = (int*)(packed + NE);                      // i32[NBUCK]
    int* bstart = bhist + NBUCK;                            // i32[NBUCK+1]
    int* bcur   = bstart + NBUCK + 1;                       // i32[NBUCK]

    hipMemsetAsync(bhist, 0, NBUCK * sizeof(int), stream);
    k_bhist<<<P1B, P1T, 0, stream>>>(ei, bhist);
    k_bscan<<<1, 1024, 0, stream>>>(bhist, bstart, bcur);
    k_p1<<<P1B, P1T, 0, stream>>>(ei, bcur, packed);
    k_deg<<<NBUCK, 256, 0, stream>>>(packed, bstart, dinv);
    k_xw<<<(NN + 63) / 64, 256, 0, stream>>>(x, W, dinv, xsh);
    k_sagg<<<NBUCK * 2, 256, 0, stream>>>(packed, bstart, xsh, b, out);
}